// Round 2
// baseline (1704.573 us; speedup 1.0000x reference)
//
#include <hip/hip_runtime.h>
#include <hip/hip_bf16.h>
#include <math.h>

typedef unsigned short ushort_t;
typedef unsigned int uint_t;
typedef __attribute__((ext_vector_type(8))) short short8;
typedef __attribute__((ext_vector_type(4))) float floatx4;

#define ALPHA 0.2f

__device__ __forceinline__ float leaky(float x) { return x >= 0.0f ? x : ALPHA * x; }

__device__ __forceinline__ float bf2f(ushort_t u) {
    union { uint_t i; float f; } v; v.i = ((uint_t)u) << 16; return v.f;
}
__device__ __forceinline__ ushort_t f2bf(float f) {
    union { float f; uint_t i; } v; v.f = f;
    uint_t x = v.i;
    uint_t lsb = (x >> 16) & 1u;
    x += 0x7fffu + lsb;            // round-to-nearest-even
    return (ushort_t)(x >> 16);
}

// ---------------- prep: norms, thetas, coefficient combos (all fp32) ----------------
// coef layout: coef[j*128 + f], f indexes concat feature space (0-63 high, 64-127 low)
__global__ void prep_kernel(const float* __restrict__ ah, const float* __restrict__ al,
                            const float* __restrict__ ch, const float* __restrict__ cl,
                            float* __restrict__ coef, float* __restrict__ consts) {
    __shared__ float red[256];
    int t = threadIdx.x;
    float va = ah[t];
    red[t] = va * va;
    __syncthreads();
    for (int s = 128; s > 0; s >>= 1) { if (t < s) red[t] += red[t + s]; __syncthreads(); }
    float sum_h = red[0];
    __syncthreads();
    float vb = al[t];
    red[t] = vb * vb;
    __syncthreads();
    for (int s = 128; s > 0; s >>= 1) { if (t < s) red[t] += red[t + s]; __syncthreads(); }
    float sum_l = red[0];

    if (t == 0) {
        consts[0] = 1.0f / sqrtf(sum_h);   // inv ||a_high||
        consts[1] = 1.0f / sqrtf(sum_l);   // inv ||a_low||
        float c = ch[0];
        float g = fminf(fmaxf(c + 3.0f, 0.0f), 6.0f) / 3.0f + 1e-6f;
        consts[2] = g * 0.5f;              // theta_high
        c = cl[0];
        g = fminf(fmaxf(c + 3.0f, 0.0f), 6.0f) / 3.0f + 1e-6f;
        consts[3] = g * 0.5f;              // theta_low
    }
    if (t < 128) {
        int f = t;
        float c0, c1, c2, c3;
        if (f < 64) {
            c0 = ah[f] + ah[128 + f] + ah[192 + f];
            c1 = ah[64 + f] + ah[128 + f] - ah[192 + f];
            c2 = al[f];
            c3 = al[64 + f];
        } else {
            int g = f - 64;
            c0 = 0.0f;
            c1 = 0.0f;
            c2 = al[128 + g] + al[192 + g];
            c3 = al[128 + g] - al[192 + g];
        }
        coef[0 * 128 + f] = c0;
        coef[1 * 128 + f] = c1;
        coef[2 * 128 + f] = c2;
        coef[3 * 128 + f] = c3;
    }
}

// ---------------- W transpose + bf16 convert: WTg[c][k] = bf16(Wcat[k][c]) ----------------
__global__ void wtrans_kernel(const float* __restrict__ Wh, const float* __restrict__ Wl,
                              ushort_t* __restrict__ WTg) {
    int c = blockIdx.x;   // 0..127
    int k = threadIdx.x;  // 0..255
    float v = (c < 64) ? Wh[k * 64 + c] : Wl[k * 64 + (c - 64)];
    WTg[c * 256 + k] = f2bf(v);
}

// ---------------- GEMM: hcat = leaky(input @ Wcat), fp32 in -> bf16 MFMA ----------------
// Block: 256 thr = 4 waves; block tile 64 rows x 128 cols; wave tile 16x128.
// WT in LDS, rows of 256 bf16, 16B chunks XOR-swizzled by (c&7) for conflict-free ds_read_b128.
__global__ __launch_bounds__(256, 2) void gemm_kernel(const float* __restrict__ in,
                                                      const ushort_t* __restrict__ WTg,
                                                      ushort_t* __restrict__ hcat, int N) {
    __shared__ ushort_t WT[128 * 256];   // 64 KiB
    int tid = threadIdx.x;
    {
        const uint_t* src = (const uint_t*)WTg;   // 128*128 dwords
        for (int i = tid; i < 128 * 128; i += 256) {
            int c = i >> 7;
            int d = i & 127;
            int chunk = d >> 2, sub = d & 3;
            int sd = ((chunk ^ (c & 7)) << 2) | sub;
            *(uint_t*)&WT[(c << 8) + (sd << 1)] = src[i];
        }
    }
    __syncthreads();

    int wave = tid >> 6, lane = tid & 63;
    int quad = lane >> 4, m16 = lane & 15;
    int rowbase = blockIdx.x * 64 + wave * 16;
    int arow = rowbase + m16;
    if (arow >= N) arow = N - 1;

    floatx4 acc[8];
#pragma unroll
    for (int ct = 0; ct < 8; ++ct) acc[ct] = (floatx4){0.0f, 0.0f, 0.0f, 0.0f};

#pragma unroll
    for (int ks = 0; ks < 8; ++ks) {
        const float* ap = in + (size_t)arow * 256 + ks * 32 + quad * 8;
        float4 a0 = *(const float4*)ap;
        float4 a1 = *(const float4*)(ap + 4);
        short8 a;
        a[0] = (short)f2bf(a0.x); a[1] = (short)f2bf(a0.y);
        a[2] = (short)f2bf(a0.z); a[3] = (short)f2bf(a0.w);
        a[4] = (short)f2bf(a1.x); a[5] = (short)f2bf(a1.y);
        a[6] = (short)f2bf(a1.z); a[7] = (short)f2bf(a1.w);
#pragma unroll
        for (int ct = 0; ct < 8; ++ct) {
            int c = ct * 16 + m16;
            int sch = (ks * 4 + quad) ^ (c & 7);
            short8 b = *(const short8*)&WT[(c << 8) + (sch << 3)];
            acc[ct] = __builtin_amdgcn_mfma_f32_16x16x32_bf16(a, b, acc[ct], 0, 0, 0);
        }
    }

#pragma unroll
    for (int ct = 0; ct < 8; ++ct) {
#pragma unroll
        for (int r = 0; r < 4; ++r) {
            int row = rowbase + quad * 4 + r;
            if (row < N) {
                float v = leaky(acc[ct][r]);
                hcat[(size_t)row * 128 + ct * 16 + m16] = f2bf(v);
            }
        }
    }
}

// ---------------- per-node scalar scores: s4[n] = hcat[n] . coef_j ----------------
__global__ void node_scores_kernel(const ushort_t* __restrict__ hcat,
                                   const float* __restrict__ coef,
                                   float* __restrict__ s4, int N) {
    int w = (blockIdx.x * blockDim.x + threadIdx.x) >> 6;
    int lane = threadIdx.x & 63;
    if (w >= N) return;
    uint_t pair = *(const uint_t*)&hcat[(size_t)w * 128 + lane * 2];
    float f0 = bf2f((ushort_t)(pair & 0xffff));
    float f1 = bf2f((ushort_t)(pair >> 16));
    int i0 = lane * 2, i1 = lane * 2 + 1;
    float p0 = f0 * coef[i0] + f1 * coef[i1];
    float p1 = f0 * coef[128 + i0] + f1 * coef[128 + i1];
    float p2 = f0 * coef[256 + i0] + f1 * coef[256 + i1];
    float p3 = f0 * coef[384 + i0] + f1 * coef[384 + i1];
#pragma unroll
    for (int off = 32; off > 0; off >>= 1) {
        p0 += __shfl_xor(p0, off);
        p1 += __shfl_xor(p1, off);
        p2 += __shfl_xor(p2, off);
        p3 += __shfl_xor(p3, off);
    }
    if (lane == 0) {
        floatx4 v = {p0, p1, p2, p3};
        *(floatx4*)&s4[(size_t)w * 4] = v;
    }
}

// ---------------- edge aggregation: wave per edge, atomics into hp/rowsums ----------------
__global__ __launch_bounds__(256) void edge_kernel(const int* __restrict__ edge,
                                                   const float* __restrict__ s4,
                                                   const ushort_t* __restrict__ hcat,
                                                   float* __restrict__ hp,
                                                   float* __restrict__ rs,
                                                   const float* __restrict__ consts,
                                                   int E, int N) {
    int w = (blockIdx.x * blockDim.x + threadIdx.x) >> 6;
    int lane = threadIdx.x & 63;
    if (w >= E) return;
    int src = edge[w];
    int dst = edge[E + w];
    floatx4 ss = *(const floatx4*)&s4[(size_t)src * 4];
    floatx4 sd = *(const floatx4*)&s4[(size_t)dst * 4];
    float zh = (ss[0] + sd[1]) * consts[0];
    float zl = (ss[2] + sd[3]) * consts[1];
    float eh = __expf(-leaky(zh));
    float el = __expf(-leaky(zl));
    if (lane == 0) unsafeAtomicAdd(&rs[src], eh);
    if (lane == 32) unsafeAtomicAdd(&rs[N + src], el);
    uint_t pair = *(const uint_t*)&hcat[(size_t)dst * 128 + lane * 2];
    float f0 = bf2f((ushort_t)(pair & 0xffff));
    float f1 = bf2f((ushort_t)(pair >> 16));
    float wgt = (lane < 32) ? eh : el;
    float* base = hp + (size_t)src * 128 + lane * 2;
    unsafeAtomicAdd(base, wgt * f0);
    unsafeAtomicAdd(base + 1, wgt * f1);
}

// ---------------- finalize: out = leaky(hp / (rowsum + theta)), fp32 out ----------------
__global__ void finalize_kernel(const float* __restrict__ hp, const float* __restrict__ rs,
                                const float* __restrict__ consts, float* __restrict__ out,
                                int N) {
    int t = blockIdx.x * blockDim.x + threadIdx.x;  // over N*32
    if (t >= N * 32) return;
    int n = t >> 5;
    int c4 = (t & 31) * 4;
    floatx4 v = *(const floatx4*)&hp[(size_t)n * 128 + c4];
    float denom = (c4 < 64) ? (rs[n] + consts[2]) : (rs[N + n] + consts[3]);
    float invd = 1.0f / denom;
    floatx4 r;
    r[0] = leaky(v[0] * invd);
    r[1] = leaky(v[1] * invd);
    r[2] = leaky(v[2] * invd);
    r[3] = leaky(v[3] * invd);
    *(floatx4*)&out[(size_t)t * 4] = r;
}

extern "C" void kernel_launch(void* const* d_in, const int* in_sizes, int n_in,
                              void* d_out, int out_size, void* d_ws, size_t ws_size,
                              hipStream_t stream) {
    const float* input = (const float*)d_in[0];
    const int* edge = (const int*)d_in[1];
    const float* Wh = (const float*)d_in[2];
    const float* Wl = (const float*)d_in[3];
    const float* ah = (const float*)d_in[4];
    const float* al = (const float*)d_in[5];
    const float* ch = (const float*)d_in[6];
    const float* cl = (const float*)d_in[7];
    int N = in_sizes[0] / 256;
    int E = in_sizes[1] / 2;
    float* out = (float*)d_out;

    char* ws = (char*)d_ws;
    size_t off = 0;
    float* hp = (float*)(ws + off);      off += (size_t)N * 128 * 4;
    float* rs = (float*)(ws + off);      off += (size_t)N * 2 * 4;
    size_t zero_bytes = off;             // hp + rowsums, contiguous
    ushort_t* hcat = (ushort_t*)(ws + off); off += (size_t)N * 128 * 2;
    float* s4 = (float*)(ws + off);      off += (size_t)N * 4 * 4;
    ushort_t* WTg = (ushort_t*)(ws + off); off += 128 * 256 * 2;
    float* coef = (float*)(ws + off);    off += 4 * 128 * 4;
    float* consts = (float*)(ws + off);  off += 64;

    hipMemsetAsync(hp, 0, zero_bytes, stream);
    prep_kernel<<<1, 256, 0, stream>>>(ah, al, ch, cl, coef, consts);
    wtrans_kernel<<<128, 256, 0, stream>>>(Wh, Wl, WTg);
    gemm_kernel<<<(N + 63) / 64, 256, 0, stream>>>(input, WTg, hcat, N);
    node_scores_kernel<<<(N + 3) / 4, 256, 0, stream>>>(hcat, coef, s4, N);
    edge_kernel<<<(E + 3) / 4, 256, 0, stream>>>(edge, s4, hcat, hp, rs, consts, E, N);
    finalize_kernel<<<(N * 32 + 255) / 256, 256, 0, stream>>>(hp, rs, consts, out, N);
}

// Round 3
// 620.651 us; speedup vs baseline: 2.7464x; 2.7464x over previous
//
#include <hip/hip_runtime.h>
#include <hip/hip_bf16.h>
#include <math.h>

typedef unsigned short ushort_t;
typedef unsigned int uint_t;
typedef __attribute__((ext_vector_type(8))) short short8;
typedef __attribute__((ext_vector_type(4))) float floatx4;

#define ALPHA 0.2f

__device__ __forceinline__ float leaky(float x) { return x >= 0.0f ? x : ALPHA * x; }

__device__ __forceinline__ float bf2f(ushort_t u) {
    union { uint_t i; float f; } v; v.i = ((uint_t)u) << 16; return v.f;
}
__device__ __forceinline__ ushort_t f2bf(float f) {
    union { float f; uint_t i; } v; v.f = f;
    uint_t x = v.i;
    uint_t lsb = (x >> 16) & 1u;
    x += 0x7fffu + lsb;            // round-to-nearest-even
    return (ushort_t)(x >> 16);
}

// ---------------- prep: norms, thetas, coefficient combos (all fp32) ----------------
__global__ void prep_kernel(const float* __restrict__ ah, const float* __restrict__ al,
                            const float* __restrict__ ch, const float* __restrict__ cl,
                            float* __restrict__ coef, float* __restrict__ consts) {
    __shared__ float red[256];
    int t = threadIdx.x;
    float va = ah[t];
    red[t] = va * va;
    __syncthreads();
    for (int s = 128; s > 0; s >>= 1) { if (t < s) red[t] += red[t + s]; __syncthreads(); }
    float sum_h = red[0];
    __syncthreads();
    float vb = al[t];
    red[t] = vb * vb;
    __syncthreads();
    for (int s = 128; s > 0; s >>= 1) { if (t < s) red[t] += red[t + s]; __syncthreads(); }
    float sum_l = red[0];

    if (t == 0) {
        consts[0] = 1.0f / sqrtf(sum_h);   // inv ||a_high||
        consts[1] = 1.0f / sqrtf(sum_l);   // inv ||a_low||
        float c = ch[0];
        float g = fminf(fmaxf(c + 3.0f, 0.0f), 6.0f) / 3.0f + 1e-6f;
        consts[2] = g * 0.5f;              // theta_high
        c = cl[0];
        g = fminf(fmaxf(c + 3.0f, 0.0f), 6.0f) / 3.0f + 1e-6f;
        consts[3] = g * 0.5f;              // theta_low
    }
    if (t < 128) {
        int f = t;
        float c0, c1, c2, c3;
        if (f < 64) {
            c0 = ah[f] + ah[128 + f] + ah[192 + f];
            c1 = ah[64 + f] + ah[128 + f] - ah[192 + f];
            c2 = al[f];
            c3 = al[64 + f];
        } else {
            int g = f - 64;
            c0 = 0.0f;
            c1 = 0.0f;
            c2 = al[128 + g] + al[192 + g];
            c3 = al[128 + g] - al[192 + g];
        }
        coef[0 * 128 + f] = c0;
        coef[1 * 128 + f] = c1;
        coef[2 * 128 + f] = c2;
        coef[3 * 128 + f] = c3;
    }
}

// ---------------- W transpose + bf16 convert ----------------
__global__ void wtrans_kernel(const float* __restrict__ Wh, const float* __restrict__ Wl,
                              ushort_t* __restrict__ WTg) {
    int c = blockIdx.x;   // 0..127
    int k = threadIdx.x;  // 0..255
    float v = (c < 64) ? Wh[k * 64 + c] : Wl[k * 64 + (c - 64)];
    WTg[c * 256 + k] = f2bf(v);
}

// ---------------- GEMM: hcat = leaky(input @ Wcat), fp32 in -> bf16 MFMA ----------------
__global__ __launch_bounds__(256, 2) void gemm_kernel(const float* __restrict__ in,
                                                      const ushort_t* __restrict__ WTg,
                                                      ushort_t* __restrict__ hcat, int N) {
    __shared__ ushort_t WT[128 * 256];   // 64 KiB
    int tid = threadIdx.x;
    {
        const uint_t* src = (const uint_t*)WTg;   // 128*128 dwords
        for (int i = tid; i < 128 * 128; i += 256) {
            int c = i >> 7;
            int d = i & 127;
            int chunk = d >> 2, sub = d & 3;
            int sd = ((chunk ^ (c & 7)) << 2) | sub;
            *(uint_t*)&WT[(c << 8) + (sd << 1)] = src[i];
        }
    }
    __syncthreads();

    int wave = tid >> 6, lane = tid & 63;
    int quad = lane >> 4, m16 = lane & 15;
    int rowbase = blockIdx.x * 64 + wave * 16;
    int arow = rowbase + m16;
    if (arow >= N) arow = N - 1;

    floatx4 acc[8];
#pragma unroll
    for (int ct = 0; ct < 8; ++ct) acc[ct] = (floatx4){0.0f, 0.0f, 0.0f, 0.0f};

#pragma unroll
    for (int ks = 0; ks < 8; ++ks) {
        const float* ap = in + (size_t)arow * 256 + ks * 32 + quad * 8;
        float4 a0 = *(const float4*)ap;
        float4 a1 = *(const float4*)(ap + 4);
        short8 a;
        a[0] = (short)f2bf(a0.x); a[1] = (short)f2bf(a0.y);
        a[2] = (short)f2bf(a0.z); a[3] = (short)f2bf(a0.w);
        a[4] = (short)f2bf(a1.x); a[5] = (short)f2bf(a1.y);
        a[6] = (short)f2bf(a1.z); a[7] = (short)f2bf(a1.w);
#pragma unroll
        for (int ct = 0; ct < 8; ++ct) {
            int c = ct * 16 + m16;
            int sch = (ks * 4 + quad) ^ (c & 7);
            short8 b = *(const short8*)&WT[(c << 8) + (sch << 3)];
            acc[ct] = __builtin_amdgcn_mfma_f32_16x16x32_bf16(a, b, acc[ct], 0, 0, 0);
        }
    }

#pragma unroll
    for (int ct = 0; ct < 8; ++ct) {
#pragma unroll
        for (int r = 0; r < 4; ++r) {
            int row = rowbase + quad * 4 + r;
            if (row < N) {
                float v = leaky(acc[ct][r]);
                hcat[(size_t)row * 128 + ct * 16 + m16] = f2bf(v);
            }
        }
    }
}

// ---------------- per-node scalar scores: s4[n] = hcat[n] . coef_j ----------------
__global__ void node_scores_kernel(const ushort_t* __restrict__ hcat,
                                   const float* __restrict__ coef,
                                   float* __restrict__ s4, int N) {
    int w = (blockIdx.x * blockDim.x + threadIdx.x) >> 6;
    int lane = threadIdx.x & 63;
    if (w >= N) return;
    uint_t pair = *(const uint_t*)&hcat[(size_t)w * 128 + lane * 2];
    float f0 = bf2f((ushort_t)(pair & 0xffff));
    float f1 = bf2f((ushort_t)(pair >> 16));
    int i0 = lane * 2, i1 = lane * 2 + 1;
    float p0 = f0 * coef[i0] + f1 * coef[i1];
    float p1 = f0 * coef[128 + i0] + f1 * coef[128 + i1];
    float p2 = f0 * coef[256 + i0] + f1 * coef[256 + i1];
    float p3 = f0 * coef[384 + i0] + f1 * coef[384 + i1];
#pragma unroll
    for (int off = 32; off > 0; off >>= 1) {
        p0 += __shfl_xor(p0, off);
        p1 += __shfl_xor(p1, off);
        p2 += __shfl_xor(p2, off);
        p3 += __shfl_xor(p3, off);
    }
    if (lane == 0) {
        floatx4 v = {p0, p1, p2, p3};
        *(floatx4*)&s4[(size_t)w * 4] = v;
    }
}

// ---------------- CSR build: histogram ----------------
__global__ void hist_kernel(const int* __restrict__ edge, int* __restrict__ deg, int E) {
    int e = blockIdx.x * blockDim.x + threadIdx.x;
    if (e < E) atomicAdd(&deg[edge[e]], 1);
}

// ---------------- CSR build: chunked prefix scan (1 block, 1024 thr) ----------------
__global__ __launch_bounds__(1024) void scan_kernel(const int* __restrict__ deg,
                                                    int* __restrict__ starts,
                                                    int* __restrict__ cursor, int N) {
    __shared__ int wsum[16];
    __shared__ int carry_s;
    int t = threadIdx.x;
    int wave = t >> 6, lane = t & 63;
    if (t == 0) carry_s = 0;
    __syncthreads();
    for (int base = 0; base < N; base += 1024) {
        int i = base + t;
        int v = (i < N) ? deg[i] : 0;
        int x = v;
#pragma unroll
        for (int off = 1; off < 64; off <<= 1) {
            int y = __shfl_up(x, off);
            if (lane >= off) x += y;
        }
        if (lane == 63) wsum[wave] = x;
        __syncthreads();                    // wsum ready; carry from prev iter visible
        int woff = 0;
#pragma unroll
        for (int w = 0; w < 16; ++w) woff += (w < wave) ? wsum[w] : 0;
        int excl = carry_s + woff + x - v;
        if (i < N) { starts[i] = excl; cursor[i] = excl; }
        __syncthreads();                    // all done reading carry_s / wsum
        if (t == 1023) carry_s += woff + x; // chunk total
        __syncthreads();                    // carry update visible next iter
    }
    if (t == 0) starts[N] = carry_s;
}

// ---------------- CSR build: scatter edges with precomputed weights ----------------
__global__ void scatter_kernel(const int* __restrict__ edge, const float* __restrict__ s4,
                               const float* __restrict__ consts, int* __restrict__ cursor,
                               float4* __restrict__ elist, int E) {
    int e = blockIdx.x * blockDim.x + threadIdx.x;
    if (e >= E) return;
    int src = edge[e];
    int dst = edge[E + e];
    float4 ss = *(const float4*)&s4[(size_t)src * 4];
    float4 sd = *(const float4*)&s4[(size_t)dst * 4];
    float eh = __expf(-leaky((ss.x + sd.y) * consts[0]));
    float el = __expf(-leaky((ss.z + sd.w) * consts[1]));
    int pos = atomicAdd(&cursor[src], 1);
    float4 rec;
    rec.x = __int_as_float(dst);
    rec.y = eh;
    rec.z = el;
    rec.w = 0.0f;
    elist[pos] = rec;
}

// ---------------- aggregate + finalize: wave per node, no atomics ----------------
__global__ __launch_bounds__(256) void aggregate_kernel(const int* __restrict__ starts,
                                                        const float4* __restrict__ elist,
                                                        const ushort_t* __restrict__ hcat,
                                                        const float* __restrict__ consts,
                                                        float* __restrict__ out, int N) {
    int w = (blockIdx.x * blockDim.x + threadIdx.x) >> 6;
    int lane = threadIdx.x & 63;
    if (w >= N) return;
    int s = starts[w];
    int e = starts[w + 1];
    bool hi = lane < 32;
    int col = lane * 2;
    float acc0 = 0.0f, acc1 = 0.0f, sh = 0.0f, sl = 0.0f;
    for (int i = s; i < e; ++i) {
        float4 rec = elist[i];                       // broadcast (same addr all lanes)
        int dst = __float_as_int(rec.x);
        uint_t pair = *(const uint_t*)&hcat[(size_t)dst * 128 + col];
        float f0 = bf2f((ushort_t)(pair & 0xffff));
        float f1 = bf2f((ushort_t)(pair >> 16));
        float wt = hi ? rec.y : rec.z;
        acc0 += wt * f0;
        acc1 += wt * f1;
        sh += rec.y;
        sl += rec.z;
    }
    float theta = hi ? consts[2] : consts[3];
    float denom = (hi ? sh : sl) + theta;
    float inv = 1.0f / denom;
    float2 r;
    r.x = leaky(acc0 * inv);
    r.y = leaky(acc1 * inv);
    *(float2*)&out[(size_t)w * 128 + col] = r;
}

extern "C" void kernel_launch(void* const* d_in, const int* in_sizes, int n_in,
                              void* d_out, int out_size, void* d_ws, size_t ws_size,
                              hipStream_t stream) {
    const float* input = (const float*)d_in[0];
    const int* edge = (const int*)d_in[1];
    const float* Wh = (const float*)d_in[2];
    const float* Wl = (const float*)d_in[3];
    const float* ah = (const float*)d_in[4];
    const float* al = (const float*)d_in[5];
    const float* ch = (const float*)d_in[6];
    const float* cl = (const float*)d_in[7];
    int N = in_sizes[0] / 256;
    int E = in_sizes[1] / 2;
    float* out = (float*)d_out;

    char* ws = (char*)d_ws;
    size_t off = 0;
    float4* elist = (float4*)(ws + off);     off += (size_t)E * 16;
    ushort_t* hcat = (ushort_t*)(ws + off);  off += (size_t)N * 128 * 2;
    float* s4 = (float*)(ws + off);          off += (size_t)N * 4 * 4;
    int* deg = (int*)(ws + off);             off += (size_t)(N + 1) * 4;
    int* starts = (int*)(ws + off);          off += (size_t)(N + 1) * 4;
    int* cursor = (int*)(ws + off);          off += (size_t)N * 4;
    ushort_t* WTg = (ushort_t*)(ws + off);   off += 128 * 256 * 2;
    float* coef = (float*)(ws + off);        off += 4 * 128 * 4;
    float* consts = (float*)(ws + off);      off += 64;

    hipMemsetAsync(deg, 0, (size_t)(N + 1) * 4, stream);
    prep_kernel<<<1, 256, 0, stream>>>(ah, al, ch, cl, coef, consts);
    wtrans_kernel<<<128, 256, 0, stream>>>(Wh, Wl, WTg);
    gemm_kernel<<<(N + 63) / 64, 256, 0, stream>>>(input, WTg, hcat, N);
    node_scores_kernel<<<(N + 3) / 4, 256, 0, stream>>>(hcat, coef, s4, N);
    hist_kernel<<<(E + 255) / 256, 256, 0, stream>>>(edge, deg, E);
    scan_kernel<<<1, 1024, 0, stream>>>(deg, starts, cursor, N);
    scatter_kernel<<<(E + 255) / 256, 256, 0, stream>>>(edge, s4, consts, cursor, elist, E);
    aggregate_kernel<<<(N + 3) / 4, 256, 0, stream>>>(starts, elist, hcat, consts, out, N);
}

// Round 4
// 474.300 us; speedup vs baseline: 3.5939x; 1.3086x over previous
//
#include <hip/hip_runtime.h>
#include <hip/hip_bf16.h>
#include <math.h>

typedef unsigned short ushort_t;
typedef unsigned int uint_t;
typedef __attribute__((ext_vector_type(8))) short short8;
typedef __attribute__((ext_vector_type(4))) float floatx4;

#define ALPHA 0.2f

__device__ __forceinline__ float leaky(float x) { return x >= 0.0f ? x : ALPHA * x; }

__device__ __forceinline__ float bf2f(ushort_t u) {
    union { uint_t i; float f; } v; v.i = ((uint_t)u) << 16; return v.f;
}
__device__ __forceinline__ ushort_t f2bf(float f) {
    union { float f; uint_t i; } v; v.f = f;
    uint_t x = v.i;
    uint_t lsb = (x >> 16) & 1u;
    x += 0x7fffu + lsb;            // round-to-nearest-even
    return (ushort_t)(x >> 16);
}

// ---------------- prep: norms, thetas, coefficient combos (all fp32) ----------------
__global__ void prep_kernel(const float* __restrict__ ah, const float* __restrict__ al,
                            const float* __restrict__ ch, const float* __restrict__ cl,
                            float* __restrict__ coef, float* __restrict__ consts) {
    __shared__ float red[256];
    int t = threadIdx.x;
    float va = ah[t];
    red[t] = va * va;
    __syncthreads();
    for (int s = 128; s > 0; s >>= 1) { if (t < s) red[t] += red[t + s]; __syncthreads(); }
    float sum_h = red[0];
    __syncthreads();
    float vb = al[t];
    red[t] = vb * vb;
    __syncthreads();
    for (int s = 128; s > 0; s >>= 1) { if (t < s) red[t] += red[t + s]; __syncthreads(); }
    float sum_l = red[0];

    if (t == 0) {
        consts[0] = 1.0f / sqrtf(sum_h);   // inv ||a_high||
        consts[1] = 1.0f / sqrtf(sum_l);   // inv ||a_low||
        float c = ch[0];
        float g = fminf(fmaxf(c + 3.0f, 0.0f), 6.0f) / 3.0f + 1e-6f;
        consts[2] = g * 0.5f;              // theta_high
        c = cl[0];
        g = fminf(fmaxf(c + 3.0f, 0.0f), 6.0f) / 3.0f + 1e-6f;
        consts[3] = g * 0.5f;              // theta_low
    }
    if (t < 128) {
        int f = t;
        float c0, c1, c2, c3;
        if (f < 64) {
            c0 = ah[f] + ah[128 + f] + ah[192 + f];
            c1 = ah[64 + f] + ah[128 + f] - ah[192 + f];
            c2 = al[f];
            c3 = al[64 + f];
        } else {
            int g = f - 64;
            c0 = 0.0f;
            c1 = 0.0f;
            c2 = al[128 + g] + al[192 + g];
            c3 = al[128 + g] - al[192 + g];
        }
        coef[0 * 128 + f] = c0;
        coef[1 * 128 + f] = c1;
        coef[2 * 128 + f] = c2;
        coef[3 * 128 + f] = c3;
    }
}

// ---------------- W transpose + bf16 convert ----------------
__global__ void wtrans_kernel(const float* __restrict__ Wh, const float* __restrict__ Wl,
                              ushort_t* __restrict__ WTg) {
    int c = blockIdx.x;   // 0..127
    int k = threadIdx.x;  // 0..255
    float v = (c < 64) ? Wh[k * 64 + c] : Wl[k * 64 + (c - 64)];
    WTg[c * 256 + k] = f2bf(v);
}

// ---------------- GEMM: hcat = leaky(input @ Wcat), fp32 in -> bf16 MFMA ----------------
__global__ __launch_bounds__(256, 2) void gemm_kernel(const float* __restrict__ in,
                                                      const ushort_t* __restrict__ WTg,
                                                      ushort_t* __restrict__ hcat, int N) {
    __shared__ ushort_t WT[128 * 256];   // 64 KiB
    int tid = threadIdx.x;
    {
        const uint_t* src = (const uint_t*)WTg;   // 128*128 dwords
        for (int i = tid; i < 128 * 128; i += 256) {
            int c = i >> 7;
            int d = i & 127;
            int chunk = d >> 2, sub = d & 3;
            int sd = ((chunk ^ (c & 7)) << 2) | sub;
            *(uint_t*)&WT[(c << 8) + (sd << 1)] = src[i];
        }
    }
    __syncthreads();

    int wave = tid >> 6, lane = tid & 63;
    int quad = lane >> 4, m16 = lane & 15;
    int rowbase = blockIdx.x * 64 + wave * 16;
    int arow = rowbase + m16;
    if (arow >= N) arow = N - 1;

    floatx4 acc[8];
#pragma unroll
    for (int ct = 0; ct < 8; ++ct) acc[ct] = (floatx4){0.0f, 0.0f, 0.0f, 0.0f};

#pragma unroll
    for (int ks = 0; ks < 8; ++ks) {
        const float* ap = in + (size_t)arow * 256 + ks * 32 + quad * 8;
        float4 a0 = *(const float4*)ap;
        float4 a1 = *(const float4*)(ap + 4);
        short8 a;
        a[0] = (short)f2bf(a0.x); a[1] = (short)f2bf(a0.y);
        a[2] = (short)f2bf(a0.z); a[3] = (short)f2bf(a0.w);
        a[4] = (short)f2bf(a1.x); a[5] = (short)f2bf(a1.y);
        a[6] = (short)f2bf(a1.z); a[7] = (short)f2bf(a1.w);
#pragma unroll
        for (int ct = 0; ct < 8; ++ct) {
            int c = ct * 16 + m16;
            int sch = (ks * 4 + quad) ^ (c & 7);
            short8 b = *(const short8*)&WT[(c << 8) + (sch << 3)];
            acc[ct] = __builtin_amdgcn_mfma_f32_16x16x32_bf16(a, b, acc[ct], 0, 0, 0);
        }
    }

#pragma unroll
    for (int ct = 0; ct < 8; ++ct) {
#pragma unroll
        for (int r = 0; r < 4; ++r) {
            int row = rowbase + quad * 4 + r;
            if (row < N) {
                float v = leaky(acc[ct][r]);
                hcat[(size_t)row * 128 + ct * 16 + m16] = f2bf(v);
            }
        }
    }
}

// ---------------- per-node scalar scores: s4[n] = hcat[n] . coef_j ----------------
__global__ void node_scores_kernel(const ushort_t* __restrict__ hcat,
                                   const float* __restrict__ coef,
                                   float* __restrict__ s4, int N) {
    int w = (blockIdx.x * blockDim.x + threadIdx.x) >> 6;
    int lane = threadIdx.x & 63;
    if (w >= N) return;
    uint_t pair = *(const uint_t*)&hcat[(size_t)w * 128 + lane * 2];
    float f0 = bf2f((ushort_t)(pair & 0xffff));
    float f1 = bf2f((ushort_t)(pair >> 16));
    int i0 = lane * 2, i1 = lane * 2 + 1;
    float p0 = f0 * coef[i0] + f1 * coef[i1];
    float p1 = f0 * coef[128 + i0] + f1 * coef[128 + i1];
    float p2 = f0 * coef[256 + i0] + f1 * coef[256 + i1];
    float p3 = f0 * coef[384 + i0] + f1 * coef[384 + i1];
#pragma unroll
    for (int off = 32; off > 0; off >>= 1) {
        p0 += __shfl_xor(p0, off);
        p1 += __shfl_xor(p1, off);
        p2 += __shfl_xor(p2, off);
        p3 += __shfl_xor(p3, off);
    }
    if (lane == 0) {
        floatx4 v = {p0, p1, p2, p3};
        *(floatx4*)&s4[(size_t)w * 4] = v;
    }
}

// ---------------- CSR build: histogram ----------------
__global__ void hist_kernel(const int* __restrict__ edge, int* __restrict__ deg, int E) {
    int e = blockIdx.x * blockDim.x + threadIdx.x;
    if (e < E) atomicAdd(&deg[edge[e]], 1);
}

// ---------------- CSR build: segment allocation (order-free, replaces prefix scan) ----------------
__global__ void alloc_kernel(const int* __restrict__ deg, int* __restrict__ starts,
                             int* __restrict__ cursor, int* __restrict__ counter, int N) {
    int i = blockIdx.x * blockDim.x + threadIdx.x;
    int lane = threadIdx.x & 63;
    int d = (i < N) ? deg[i] : 0;
    int x = d;   // inclusive wave scan
#pragma unroll
    for (int off = 1; off < 64; off <<= 1) {
        int y = __shfl_up(x, off);
        if (lane >= off) x += y;
    }
    int total = __shfl(x, 63);
    int base = 0;
    if (lane == 63) base = atomicAdd(counter, total);
    base = __shfl(base, 63);
    int pos = base + x - d;
    if (i < N) { starts[i] = pos; cursor[i] = pos; }
}

// ---------------- CSR build: scatter edges with precomputed weights ----------------
__global__ void scatter_kernel(const int* __restrict__ edge, const float* __restrict__ s4,
                               const float* __restrict__ consts, int* __restrict__ cursor,
                               float4* __restrict__ elist, int E) {
    int e = blockIdx.x * blockDim.x + threadIdx.x;
    if (e >= E) return;
    int src = edge[e];
    int dst = edge[E + e];
    float4 ss = *(const float4*)&s4[(size_t)src * 4];
    float4 sd = *(const float4*)&s4[(size_t)dst * 4];
    float eh = __expf(-leaky((ss.x + sd.y) * consts[0]));
    float el = __expf(-leaky((ss.z + sd.w) * consts[1]));
    int pos = atomicAdd(&cursor[src], 1);
    float4 rec;
    rec.x = __int_as_float(dst);
    rec.y = eh;
    rec.z = el;
    rec.w = 0.0f;
    elist[pos] = rec;
}

// ---------------- aggregate + finalize: wave per node, 4-deep gather pipeline ----------------
__global__ __launch_bounds__(256) void aggregate_kernel(const int* __restrict__ starts,
                                                        const int* __restrict__ deg,
                                                        const float4* __restrict__ elist,
                                                        const ushort_t* __restrict__ hcat,
                                                        const float* __restrict__ consts,
                                                        float* __restrict__ out, int N) {
    int w = (blockIdx.x * blockDim.x + threadIdx.x) >> 6;
    int lane = threadIdx.x & 63;
    if (w >= N) return;
    int s = starts[w];
    int e = s + deg[w];
    bool hi = lane < 32;
    int col = lane * 2;

    // 4 independent accumulator slots to allow 4 gathers in flight
    float A0 = 0, A1 = 0, SH0 = 0, SL0 = 0;
    float B0 = 0, B1 = 0, SH1 = 0, SL1 = 0;
    float C0 = 0, C1 = 0, SH2 = 0, SL2 = 0;
    float D0 = 0, D1 = 0, SH3 = 0, SL3 = 0;

    int i = s;
    for (; i + 4 <= e; i += 4) {
        float4 r0 = elist[i];
        float4 r1 = elist[i + 1];
        float4 r2 = elist[i + 2];
        float4 r3 = elist[i + 3];
        uint_t p0 = *(const uint_t*)&hcat[(size_t)__float_as_int(r0.x) * 128 + col];
        uint_t p1 = *(const uint_t*)&hcat[(size_t)__float_as_int(r1.x) * 128 + col];
        uint_t p2 = *(const uint_t*)&hcat[(size_t)__float_as_int(r2.x) * 128 + col];
        uint_t p3 = *(const uint_t*)&hcat[(size_t)__float_as_int(r3.x) * 128 + col];
        float w0 = hi ? r0.y : r0.z;
        float w1 = hi ? r1.y : r1.z;
        float w2 = hi ? r2.y : r2.z;
        float w3 = hi ? r3.y : r3.z;
        A0 += w0 * bf2f((ushort_t)(p0 & 0xffff)); A1 += w0 * bf2f((ushort_t)(p0 >> 16));
        B0 += w1 * bf2f((ushort_t)(p1 & 0xffff)); B1 += w1 * bf2f((ushort_t)(p1 >> 16));
        C0 += w2 * bf2f((ushort_t)(p2 & 0xffff)); C1 += w2 * bf2f((ushort_t)(p2 >> 16));
        D0 += w3 * bf2f((ushort_t)(p3 & 0xffff)); D1 += w3 * bf2f((ushort_t)(p3 >> 16));
        SH0 += r0.y; SL0 += r0.z;
        SH1 += r1.y; SL1 += r1.z;
        SH2 += r2.y; SL2 += r2.z;
        SH3 += r3.y; SL3 += r3.z;
    }
    for (; i < e; ++i) {
        float4 r0 = elist[i];
        uint_t p0 = *(const uint_t*)&hcat[(size_t)__float_as_int(r0.x) * 128 + col];
        float w0 = hi ? r0.y : r0.z;
        A0 += w0 * bf2f((ushort_t)(p0 & 0xffff)); A1 += w0 * bf2f((ushort_t)(p0 >> 16));
        SH0 += r0.y; SL0 += r0.z;
    }

    float acc0 = (A0 + B0) + (C0 + D0);
    float acc1 = (A1 + B1) + (C1 + D1);
    float sh = (SH0 + SH1) + (SH2 + SH3);
    float sl = (SL0 + SL1) + (SL2 + SL3);

    float theta = hi ? consts[2] : consts[3];
    float denom = (hi ? sh : sl) + theta;
    float inv = 1.0f / denom;
    float2 r;
    r.x = leaky(acc0 * inv);
    r.y = leaky(acc1 * inv);
    *(float2*)&out[(size_t)w * 128 + col] = r;
}

extern "C" void kernel_launch(void* const* d_in, const int* in_sizes, int n_in,
                              void* d_out, int out_size, void* d_ws, size_t ws_size,
                              hipStream_t stream) {
    const float* input = (const float*)d_in[0];
    const int* edge = (const int*)d_in[1];
    const float* Wh = (const float*)d_in[2];
    const float* Wl = (const float*)d_in[3];
    const float* ah = (const float*)d_in[4];
    const float* al = (const float*)d_in[5];
    const float* ch = (const float*)d_in[6];
    const float* cl = (const float*)d_in[7];
    int N = in_sizes[0] / 256;
    int E = in_sizes[1] / 2;
    float* out = (float*)d_out;

    char* ws = (char*)d_ws;
    size_t off = 0;
    float4* elist = (float4*)(ws + off);     off += (size_t)E * 16;
    ushort_t* hcat = (ushort_t*)(ws + off);  off += (size_t)N * 128 * 2;
    float* s4 = (float*)(ws + off);          off += (size_t)N * 4 * 4;
    int* deg = (int*)(ws + off);             off += (size_t)N * 4;
    int* counter = (int*)(ws + off);         off += 4;
    size_t zero_bytes = (size_t)(N + 1) * 4; // deg + counter contiguous
    int* starts = (int*)(ws + off);          off += (size_t)N * 4;
    int* cursor = (int*)(ws + off);          off += (size_t)N * 4;
    ushort_t* WTg = (ushort_t*)(ws + off);   off += 128 * 256 * 2;
    float* coef = (float*)(ws + off);        off += 4 * 128 * 4;
    float* consts = (float*)(ws + off);      off += 64;

    hipMemsetAsync(deg, 0, zero_bytes, stream);
    prep_kernel<<<1, 256, 0, stream>>>(ah, al, ch, cl, coef, consts);
    wtrans_kernel<<<128, 256, 0, stream>>>(Wh, Wl, WTg);
    gemm_kernel<<<(N + 63) / 64, 256, 0, stream>>>(input, WTg, hcat, N);
    node_scores_kernel<<<(N + 3) / 4, 256, 0, stream>>>(hcat, coef, s4, N);
    hist_kernel<<<(E + 255) / 256, 256, 0, stream>>>(edge, deg, E);
    alloc_kernel<<<(N + 255) / 256, 256, 0, stream>>>(deg, starts, cursor, counter, N);
    scatter_kernel<<<(E + 255) / 256, 256, 0, stream>>>(edge, s4, consts, cursor, elist, E);
    aggregate_kernel<<<(N + 3) / 4, 256, 0, stream>>>(starts, deg, elist, hcat, consts, out, N);
}

// Round 5
// 465.027 us; speedup vs baseline: 3.6655x; 1.0199x over previous
//
#include <hip/hip_runtime.h>
#include <hip/hip_bf16.h>
#include <hip/hip_fp16.h>
#include <math.h>

typedef unsigned short ushort_t;
typedef unsigned int uint_t;
typedef __attribute__((ext_vector_type(8))) short short8;
typedef __attribute__((ext_vector_type(4))) float floatx4;

#define ALPHA 0.2f

__device__ __forceinline__ float leaky(float x) { return x >= 0.0f ? x : ALPHA * x; }

__device__ __forceinline__ float bf2f(ushort_t u) {
    union { uint_t i; float f; } v; v.i = ((uint_t)u) << 16; return v.f;
}
__device__ __forceinline__ ushort_t f2bf(float f) {
    union { float f; uint_t i; } v; v.f = f;
    uint_t x = v.i;
    uint_t lsb = (x >> 16) & 1u;
    x += 0x7fffu + lsb;            // round-to-nearest-even
    return (ushort_t)(x >> 16);
}

// ---------------- prep: norms, thetas, coefficient combos (all fp32) ----------------
__global__ void prep_kernel(const float* __restrict__ ah, const float* __restrict__ al,
                            const float* __restrict__ ch, const float* __restrict__ cl,
                            float* __restrict__ coef, float* __restrict__ consts) {
    __shared__ float red[256];
    int t = threadIdx.x;
    float va = ah[t];
    red[t] = va * va;
    __syncthreads();
    for (int s = 128; s > 0; s >>= 1) { if (t < s) red[t] += red[t + s]; __syncthreads(); }
    float sum_h = red[0];
    __syncthreads();
    float vb = al[t];
    red[t] = vb * vb;
    __syncthreads();
    for (int s = 128; s > 0; s >>= 1) { if (t < s) red[t] += red[t + s]; __syncthreads(); }
    float sum_l = red[0];

    if (t == 0) {
        consts[0] = 1.0f / sqrtf(sum_h);   // inv ||a_high||
        consts[1] = 1.0f / sqrtf(sum_l);   // inv ||a_low||
        float c = ch[0];
        float g = fminf(fmaxf(c + 3.0f, 0.0f), 6.0f) / 3.0f + 1e-6f;
        consts[2] = g * 0.5f;              // theta_high
        c = cl[0];
        g = fminf(fmaxf(c + 3.0f, 0.0f), 6.0f) / 3.0f + 1e-6f;
        consts[3] = g * 0.5f;              // theta_low
    }
    if (t < 128) {
        int f = t;
        float c0, c1, c2, c3;
        if (f < 64) {
            c0 = ah[f] + ah[128 + f] + ah[192 + f];
            c1 = ah[64 + f] + ah[128 + f] - ah[192 + f];
            c2 = al[f];
            c3 = al[64 + f];
        } else {
            int g = f - 64;
            c0 = 0.0f;
            c1 = 0.0f;
            c2 = al[128 + g] + al[192 + g];
            c3 = al[128 + g] - al[192 + g];
        }
        coef[0 * 128 + f] = c0;
        coef[1 * 128 + f] = c1;
        coef[2 * 128 + f] = c2;
        coef[3 * 128 + f] = c3;
    }
}

// ---------------- W transpose + bf16 convert ----------------
__global__ void wtrans_kernel(const float* __restrict__ Wh, const float* __restrict__ Wl,
                              ushort_t* __restrict__ WTg) {
    int c = blockIdx.x;   // 0..127
    int k = threadIdx.x;  // 0..255
    float v = (c < 64) ? Wh[k * 64 + c] : Wl[k * 64 + (c - 64)];
    WTg[c * 256 + k] = f2bf(v);
}

// ---------------- GEMM: hcat = leaky(input @ Wcat), fp32 in -> bf16 MFMA ----------------
// 32 KiB LDS (one K-half at a time) -> 4 blocks/CU. uint4 staging; 16B-chunk XOR swizzle.
__global__ __launch_bounds__(256, 4) void gemm_kernel(const float* __restrict__ in,
                                                      const ushort_t* __restrict__ WTg,
                                                      ushort_t* __restrict__ hcat, int N) {
    __shared__ ushort_t WT[128 * 128];   // 32 KiB: 128 cols x 128 k (one half)
    int tid = threadIdx.x;
    int wave = tid >> 6, lane = tid & 63;
    int quad = lane >> 4, m16 = lane & 15;
    int rowbase = blockIdx.x * 64 + wave * 16;
    int arow = rowbase + m16;
    if (arow >= N) arow = N - 1;

    floatx4 acc[8];
#pragma unroll
    for (int ct = 0; ct < 8; ++ct) acc[ct] = (floatx4){0.0f, 0.0f, 0.0f, 0.0f};

    const uint4* WTg4 = (const uint4*)WTg;   // 32 uint4 per col-row of 256 bf16

#pragma unroll
    for (int kh = 0; kh < 2; ++kh) {
        if (kh) __syncthreads();             // protect WT before restaging
        // stage this K-half: 128 cols x 16 chunks(16B) = 2048 uint4
        for (int i = tid; i < 2048; i += 256) {
            int c = i >> 4, j = i & 15;
            int sj = j ^ (c & 7);
            uint4 v = WTg4[c * 32 + kh * 16 + j];
            *(uint4*)&WT[c * 128 + sj * 8] = v;
        }
        __syncthreads();
#pragma unroll
        for (int ks = 0; ks < 4; ++ks) {
            const float* ap = in + (size_t)arow * 256 + kh * 128 + ks * 32 + quad * 8;
            float4 a0 = *(const float4*)ap;
            float4 a1 = *(const float4*)(ap + 4);
            short8 a;
            a[0] = (short)f2bf(a0.x); a[1] = (short)f2bf(a0.y);
            a[2] = (short)f2bf(a0.z); a[3] = (short)f2bf(a0.w);
            a[4] = (short)f2bf(a1.x); a[5] = (short)f2bf(a1.y);
            a[6] = (short)f2bf(a1.z); a[7] = (short)f2bf(a1.w);
#pragma unroll
            for (int ct = 0; ct < 8; ++ct) {
                int c = ct * 16 + m16;
                int sch = (ks * 4 + quad) ^ (c & 7);
                short8 b = *(const short8*)&WT[c * 128 + sch * 8];
                acc[ct] = __builtin_amdgcn_mfma_f32_16x16x32_bf16(a, b, acc[ct], 0, 0, 0);
            }
        }
    }

#pragma unroll
    for (int ct = 0; ct < 8; ++ct) {
#pragma unroll
        for (int r = 0; r < 4; ++r) {
            int row = rowbase + quad * 4 + r;
            if (row < N) {
                float v = leaky(acc[ct][r]);
                hcat[(size_t)row * 128 + ct * 16 + m16] = f2bf(v);
            }
        }
    }
}

// ---------------- per-node scalar scores: s4[n] = hcat[n] . coef_j ----------------
__global__ void node_scores_kernel(const ushort_t* __restrict__ hcat,
                                   const float* __restrict__ coef,
                                   float* __restrict__ s4, int N) {
    int w = (blockIdx.x * blockDim.x + threadIdx.x) >> 6;
    int lane = threadIdx.x & 63;
    if (w >= N) return;
    uint_t pair = *(const uint_t*)&hcat[(size_t)w * 128 + lane * 2];
    float f0 = bf2f((ushort_t)(pair & 0xffff));
    float f1 = bf2f((ushort_t)(pair >> 16));
    int i0 = lane * 2, i1 = lane * 2 + 1;
    float p0 = f0 * coef[i0] + f1 * coef[i1];
    float p1 = f0 * coef[128 + i0] + f1 * coef[128 + i1];
    float p2 = f0 * coef[256 + i0] + f1 * coef[256 + i1];
    float p3 = f0 * coef[384 + i0] + f1 * coef[384 + i1];
#pragma unroll
    for (int off = 32; off > 0; off >>= 1) {
        p0 += __shfl_xor(p0, off);
        p1 += __shfl_xor(p1, off);
        p2 += __shfl_xor(p2, off);
        p3 += __shfl_xor(p3, off);
    }
    if (lane == 0) {
        floatx4 v = {p0, p1, p2, p3};
        *(floatx4*)&s4[(size_t)w * 4] = v;
    }
}

// ---------------- CSR build: histogram ----------------
__global__ void hist_kernel(const int* __restrict__ edge, int* __restrict__ deg, int E) {
    int e = blockIdx.x * blockDim.x + threadIdx.x;
    if (e < E) atomicAdd(&deg[edge[e]], 1);
}

// ---------------- CSR build: segment allocation (order-free) ----------------
__global__ void alloc_kernel(const int* __restrict__ deg, int* __restrict__ starts,
                             int* __restrict__ cursor, int* __restrict__ counter, int N) {
    int i = blockIdx.x * blockDim.x + threadIdx.x;
    int lane = threadIdx.x & 63;
    int d = (i < N) ? deg[i] : 0;
    int x = d;   // inclusive wave scan
#pragma unroll
    for (int off = 1; off < 64; off <<= 1) {
        int y = __shfl_up(x, off);
        if (lane >= off) x += y;
    }
    int total = __shfl(x, 63);
    int base = 0;
    if (lane == 63) base = atomicAdd(counter, total);
    base = __shfl(base, 63);
    int pos = base + x - d;
    if (i < N) { starts[i] = pos; cursor[i] = pos; }
}

// ---------------- CSR build: scatter 8B records {dst, half2(eh,el)} ----------------
__global__ void scatter_kernel(const int* __restrict__ edge, const float* __restrict__ s4,
                               const float* __restrict__ consts, int* __restrict__ cursor,
                               uint2* __restrict__ elist, int E) {
    int e = blockIdx.x * blockDim.x + threadIdx.x;
    if (e >= E) return;
    int src = edge[e];
    int dst = edge[E + e];
    float4 ss = *(const float4*)&s4[(size_t)src * 4];
    float4 sd = *(const float4*)&s4[(size_t)dst * 4];
    float eh = __expf(-leaky((ss.x + sd.y) * consts[0]));
    float el = __expf(-leaky((ss.z + sd.w) * consts[1]));
    int pos = atomicAdd(&cursor[src], 1);
    uint_t he = __half_as_ushort(__float2half(eh));
    uint_t hl = __half_as_ushort(__float2half(el));
    uint2 rec;
    rec.x = (uint_t)dst;
    rec.y = (uint_t)he | ((uint_t)hl << 16);
    elist[pos] = rec;
}

// ---------------- aggregate + finalize: wave per node, 8-deep gather pipeline ----------------
__global__ __launch_bounds__(256) void aggregate_kernel(const int* __restrict__ starts,
                                                        const int* __restrict__ deg,
                                                        const uint2* __restrict__ elist,
                                                        const ushort_t* __restrict__ hcat,
                                                        const float* __restrict__ consts,
                                                        float* __restrict__ out, int N) {
    int w = (blockIdx.x * blockDim.x + threadIdx.x) >> 6;
    int lane = threadIdx.x & 63;
    if (w >= N) return;
    int s = starts[w];
    int e = s + deg[w];
    bool hi = lane < 32;
    int col = lane * 2;

    float a0 = 0, a1 = 0, b0 = 0, b1 = 0;
    float sh0 = 0, sl0 = 0, sh1 = 0, sl1 = 0;

    int i = s;
    for (; i + 8 <= e; i += 8) {
        uint2 rr[8];
#pragma unroll
        for (int j = 0; j < 8; ++j) rr[j] = elist[i + j];
        uint_t pp[8];
#pragma unroll
        for (int j = 0; j < 8; ++j)
            pp[j] = *(const uint_t*)&hcat[(size_t)(int)rr[j].x * 128 + col];
#pragma unroll
        for (int j = 0; j < 8; ++j) {
            float eh = __half2float(__ushort_as_half((ushort_t)(rr[j].y & 0xffff)));
            float el = __half2float(__ushort_as_half((ushort_t)(rr[j].y >> 16)));
            float wt = hi ? eh : el;
            float f0 = bf2f((ushort_t)(pp[j] & 0xffff));
            float f1 = bf2f((ushort_t)(pp[j] >> 16));
            if (j & 1) { b0 += wt * f0; b1 += wt * f1; sh1 += eh; sl1 += el; }
            else       { a0 += wt * f0; a1 += wt * f1; sh0 += eh; sl0 += el; }
        }
    }
    for (; i < e; ++i) {
        uint2 r = elist[i];
        uint_t p = *(const uint_t*)&hcat[(size_t)(int)r.x * 128 + col];
        float eh = __half2float(__ushort_as_half((ushort_t)(r.y & 0xffff)));
        float el = __half2float(__ushort_as_half((ushort_t)(r.y >> 16)));
        float wt = hi ? eh : el;
        a0 += wt * bf2f((ushort_t)(p & 0xffff));
        a1 += wt * bf2f((ushort_t)(p >> 16));
        sh0 += eh; sl0 += el;
    }

    float acc0 = a0 + b0;
    float acc1 = a1 + b1;
    float sh = sh0 + sh1;
    float sl = sl0 + sl1;

    float theta = hi ? consts[2] : consts[3];
    float denom = (hi ? sh : sl) + theta;
    float inv = 1.0f / denom;
    float2 r;
    r.x = leaky(acc0 * inv);
    r.y = leaky(acc1 * inv);
    *(float2*)&out[(size_t)w * 128 + col] = r;
}

extern "C" void kernel_launch(void* const* d_in, const int* in_sizes, int n_in,
                              void* d_out, int out_size, void* d_ws, size_t ws_size,
                              hipStream_t stream) {
    const float* input = (const float*)d_in[0];
    const int* edge = (const int*)d_in[1];
    const float* Wh = (const float*)d_in[2];
    const float* Wl = (const float*)d_in[3];
    const float* ah = (const float*)d_in[4];
    const float* al = (const float*)d_in[5];
    const float* ch = (const float*)d_in[6];
    const float* cl = (const float*)d_in[7];
    int N = in_sizes[0] / 256;
    int E = in_sizes[1] / 2;
    float* out = (float*)d_out;

    char* ws = (char*)d_ws;
    size_t off = 0;
    uint2* elist = (uint2*)(ws + off);       off += (size_t)E * 8;
    ushort_t* hcat = (ushort_t*)(ws + off);  off += (size_t)N * 128 * 2;
    float* s4 = (float*)(ws + off);          off += (size_t)N * 4 * 4;
    int* deg = (int*)(ws + off);             off += (size_t)N * 4;
    int* counter = (int*)(ws + off);         off += 4;
    size_t zero_bytes = (size_t)(N + 1) * 4; // deg + counter contiguous
    int* starts = (int*)(ws + off);          off += (size_t)N * 4;
    int* cursor = (int*)(ws + off);          off += (size_t)N * 4;
    ushort_t* WTg = (ushort_t*)(ws + off);   off += 128 * 256 * 2;
    float* coef = (float*)(ws + off);        off += 4 * 128 * 4;
    float* consts = (float*)(ws + off);      off += 64;

    hipMemsetAsync(deg, 0, zero_bytes, stream);
    prep_kernel<<<1, 256, 0, stream>>>(ah, al, ch, cl, coef, consts);
    wtrans_kernel<<<128, 256, 0, stream>>>(Wh, Wl, WTg);
    gemm_kernel<<<(N + 63) / 64, 256, 0, stream>>>(input, WTg, hcat, N);
    node_scores_kernel<<<(N + 3) / 4, 256, 0, stream>>>(hcat, coef, s4, N);
    hist_kernel<<<(E + 255) / 256, 256, 0, stream>>>(edge, deg, E);
    alloc_kernel<<<(N + 255) / 256, 256, 0, stream>>>(deg, starts, cursor, counter, N);
    scatter_kernel<<<(E + 255) / 256, 256, 0, stream>>>(edge, s4, consts, cursor, elist, E);
    aggregate_kernel<<<(N + 3) / 4, 256, 0, stream>>>(starts, deg, elist, hcat, consts, out, N);
}